// Round 3
// baseline (57.737 us; speedup 1.0000x reference)
//
#include <hip/hip_runtime.h>
#include <hip/hip_bf16.h>

#define BDIM 512

typedef __attribute__((ext_vector_type(8))) _Float16 f16x8;
typedef __attribute__((ext_vector_type(4))) _Float16 f16x4;
typedef __attribute__((ext_vector_type(4))) float f32x4;

// RoPE cos/sin table: tab[t*32+u] = (cos(t*invf_u), sin(t*invf_u)), t in [0,256), u in [0,32).
__global__ void rope_tab_kernel(float2* __restrict__ tab) {
    int idx = blockIdx.x * 256 + threadIdx.x;      // 8192 entries
    int t = idx >> 5, u = idx & 31;
    float inv = __expf((float)u * -0.28782313662425572f);  // 10000^(-u/32)
    float sn, cs;
    sincosf((float)t * inv, &sn, &cs);
    tab[idx] = make_float2(cs, sn);
}

// Local windowed attention with RoPE. b=32, n=4096, d=64, WINDOW=128, 1 backward window.
// One block per (batch, window): Q[128x64] x K/V[256x64]. 512 threads = 8 waves.
// QK^T swapped: D = mfma(K,Q) -> each lane holds P[i=c][j] -> softmax via shfl(16,32),
// P feeds PV from registers. LDS: K and V share ONE 36.9KB buffer (4 blocks/CU);
// V is prefetched to registers before QK^T and written to LDS after the K phase.
template<bool USE_TAB>
__global__ __launch_bounds__(512, 4)
void la_kernel(const float* __restrict__ qg, const float* __restrict__ kg,
               const float* __restrict__ vg, float* __restrict__ outg,
               const float2* __restrict__ tab)
{
    __shared__ _Float16 smem[256 * 72];            // 36864 B, aliased K then V
    _Float16 (*Ks)[72]  = (_Float16(*)[72])smem;   // stride 144B
    _Float16 (*Vt)[276] = (_Float16(*)[276])smem;  // 64 rows x 552B = 35328 B

    const int ww = blockIdx.x, bb = blockIdx.y;
    const int tid = threadIdx.x;
    const size_t qbase = ((size_t)bb * 4096 + (size_t)ww * 128) * 64;
    const float NEG = -3.0e38f;
    const float NLT32 = -0.28782313662425572f;
    const int srow0 = ww * 128 - 128;              // first source row of K/V (may be <0)

    const int wv = tid >> 6, lane = tid & 63, g = lane >> 4, c = lane & 15;
    const int qrow = wv * 16 + c;

    // ---- V prefetch to registers (float4 x8), transposed-write later ----
    float4 vf[8];
    #pragma unroll
    for (int tt = 0; tt < 2; ++tt) {
        int task = tid + tt * 512;
        int eq = task & 15, jq = task >> 4;        // jq in [0,64)
        #pragma unroll
        for (int u = 0; u < 4; ++u) {
            int src = srow0 + 4 * jq + u;
            float4 z = {0.f, 0.f, 0.f, 0.f};
            vf[tt * 4 + u] = (src >= 0)
                ? *(const float4*)(vg + ((size_t)bb * 4096 + src) * 64 + 4 * eq) : z;
        }
    }

    // ---- per-lane Q load + RoPE (t = 128 + qrow) ----
    f16x8 qa0, qa1;
    {
        const float* p = qg + qbase + (size_t)qrow * 64 + 8 * g;
        float4 a0 = *(const float4*)p;
        float4 a1 = *(const float4*)(p + 4);
        float4 b0 = *(const float4*)(p + 32);
        float4 b1 = *(const float4*)(p + 36);
        float ra[8] = {a0.x,a0.y,a0.z,a0.w,a1.x,a1.y,a1.z,a1.w};
        float rb[8] = {b0.x,b0.y,b0.z,b0.w,b1.x,b1.y,b1.z,b1.w};
        float tq = (float)(128 + qrow);
        #pragma unroll
        for (int u = 0; u < 8; ++u) {
            float sn, cs;
            if (USE_TAB) {
                float2 t2 = tab[(128 + qrow) * 32 + 8 * g + u];
                cs = t2.x; sn = t2.y;
            } else {
                float invf = __expf((float)(8 * g + u) * NLT32);
                __sincosf(tq * invf, &sn, &cs);
            }
            float a = ra[u] * 0.125f, b = rb[u] * 0.125f;
            qa0[u] = (_Float16)(a * cs - b * sn);
            qa1[u] = (_Float16)(b * cs + a * sn);
        }
    }

    // ---- K staging with RoPE (t = j) ----
    #pragma unroll
    for (int it = 0; it < 4; ++it) {
        int task = tid + it * 512;                 // 2048 tasks
        int j = task >> 3, cb = (task & 7) << 2;
        float4 x1 = {0.f,0.f,0.f,0.f}, x2 = {0.f,0.f,0.f,0.f};
        int src = srow0 + j;
        if (src >= 0) {
            const float* p = kg + ((size_t)bb * 4096 + src) * 64 + cb;
            x1 = *(const float4*)p;
            x2 = *(const float4*)(p + 32);
        }
        const float* x1p = &x1.x;
        const float* x2p = &x2.x;
        f16x4 lo, hi;
        #pragma unroll
        for (int u = 0; u < 4; ++u) {
            float sn, cs;
            if (USE_TAB) {
                float2 t2 = tab[j * 32 + cb + u];
                cs = t2.x; sn = t2.y;
            } else {
                float invf = __expf((float)(cb + u) * NLT32);
                __sincosf((float)j * invf, &sn, &cs);
            }
            lo[u] = (_Float16)(x1p[u] * cs - x2p[u] * sn);
            hi[u] = (_Float16)(x2p[u] * cs + x1p[u] * sn);
        }
        *(f16x4*)&Ks[j][cb]      = lo;
        *(f16x4*)&Ks[j][cb + 32] = hi;
    }

    __syncthreads();

    // ---- QK^T (swapped): acc[jt] holds D[j = 16jt+4g+r][i = c] ----
    f32x4 acc[16];
    #pragma unroll
    for (int jt = 0; jt < 16; ++jt) acc[jt] = (f32x4){0.f,0.f,0.f,0.f};

    #pragma unroll
    for (int jt = 0; jt < 16; ++jt) {
        if (jt <= wv + 8) {                        // wave-uniform: rest fully masked
            f16x8 kb0 = *(const f16x8*)&Ks[jt * 16 + c][8 * g];
            f16x8 kb1 = *(const f16x8*)&Ks[jt * 16 + c][32 + 8 * g];
            acc[jt] = __builtin_amdgcn_mfma_f32_16x16x32_f16(kb0, qa0, acc[jt], 0, 0, 0);
            acc[jt] = __builtin_amdgcn_mfma_f32_16x16x32_f16(kb1, qa1, acc[jt], 0, 0, 0);
        }
    }

    // ---- mask + softmax over j for row i = qrow ----
    const bool w0 = (ww == 0);
    #pragma unroll
    for (int jt = 0; jt < 16; ++jt) {
        #pragma unroll
        for (int r = 0; r < 4; ++r) {
            int j = jt * 16 + 4 * g + r;
            if ((j > qrow + 128) || (w0 && j < 128)) acc[jt][r] = NEG;
        }
    }

    float m = NEG;
    #pragma unroll
    for (int jt = 0; jt < 16; ++jt)
        #pragma unroll
        for (int r = 0; r < 4; ++r) m = fmaxf(m, acc[jt][r]);
    m = fmaxf(m, __shfl_xor(m, 16));
    m = fmaxf(m, __shfl_xor(m, 32));

    float s = 0.f;
    #pragma unroll
    for (int jt = 0; jt < 16; ++jt) {
        #pragma unroll
        for (int r = 0; r < 4; ++r) {
            float p = __expf(acc[jt][r] - m);
            acc[jt][r] = p;
            s += p;
        }
    }
    s += __shfl_xor(s, 16);
    s += __shfl_xor(s, 32);
    float rcp = 1.0f / s;

    // P -> f16 fragments (frees acc)
    f16x8 pa[8];
    #pragma unroll
    for (int s8 = 0; s8 < 8; ++s8)
        #pragma unroll
        for (int r = 0; r < 4; ++r) {
            pa[s8][r]     = (_Float16)(acc[2 * s8][r] * rcp);
            pa[s8][r + 4] = (_Float16)(acc[2 * s8 + 1][r] * rcp);
        }

    __syncthreads();                               // all K reads done -> reuse buffer for V

    // ---- V: convert + transposed write (4x4 blocks, b64 stores) ----
    #pragma unroll
    for (int tt = 0; tt < 2; ++tt) {
        int task = tid + tt * 512;
        int eq = task & 15, jq = task >> 4;
        const float* f0 = (const float*)&vf[tt * 4 + 0];
        const float* f1 = (const float*)&vf[tt * 4 + 1];
        const float* f2 = (const float*)&vf[tt * 4 + 2];
        const float* f3 = (const float*)&vf[tt * 4 + 3];
        #pragma unroll
        for (int w = 0; w < 4; ++w) {
            f16x4 o;
            o[0] = (_Float16)f0[w]; o[1] = (_Float16)f1[w];
            o[2] = (_Float16)f2[w]; o[3] = (_Float16)f3[w];
            *(f16x4*)&Vt[4 * eq + w][4 * jq] = o;
        }
    }

    __syncthreads();

    // ---- PV: A = P (regs), B = V with the SAME j-slot permutation ----
    f32x4 accO[4];
    #pragma unroll
    for (int nt = 0; nt < 4; ++nt) accO[nt] = (f32x4){0.f,0.f,0.f,0.f};

    #pragma unroll
    for (int s8 = 0; s8 < 8; ++s8) {
        if (32 * s8 <= 16 * wv + 143) {            // wave-uniform: rest have P == 0
            #pragma unroll
            for (int nt = 0; nt < 4; ++nt) {
                f16x4 vb0 = *(const f16x4*)&Vt[nt * 16 + c][s8 * 32 + 4 * g];
                f16x4 vb1 = *(const f16x4*)&Vt[nt * 16 + c][s8 * 32 + 16 + 4 * g];
                f16x8 vb;
                #pragma unroll
                for (int u = 0; u < 4; ++u) { vb[u] = vb0[u]; vb[u + 4] = vb1[u]; }
                accO[nt] = __builtin_amdgcn_mfma_f32_16x16x32_f16(pa[s8], vb, accO[nt], 0, 0, 0);
            }
        }
    }

    // ---- store: i = wv*16 + 4g + r, e = nt*16 + c ----
    float* op = outg + qbase + (size_t)(wv * 16) * 64;
    #pragma unroll
    for (int nt = 0; nt < 4; ++nt)
        #pragma unroll
        for (int r = 0; r < 4; ++r)
            op[(size_t)(4 * g + r) * 64 + nt * 16 + c] = accO[nt][r];
}

extern "C" void kernel_launch(void* const* d_in, const int* in_sizes, int n_in,
                              void* d_out, int out_size, void* d_ws, size_t ws_size,
                              hipStream_t stream) {
    (void)in_sizes; (void)n_in; (void)out_size;
    const float* q = (const float*)d_in[0];
    const float* k = (const float*)d_in[1];
    const float* v = (const float*)d_in[2];
    float* out = (float*)d_out;
    dim3 grid(32, 32);  // x = window, y = batch

    if (ws_size >= 8192 * sizeof(float2)) {
        float2* tab = (float2*)d_ws;
        rope_tab_kernel<<<32, 256, 0, stream>>>(tab);
        la_kernel<true><<<grid, BDIM, 0, stream>>>(q, k, v, out, tab);
    } else {
        la_kernel<false><<<grid, BDIM, 0, stream>>>(q, k, v, out, nullptr);
    }
}

// Round 4
// 50.983 us; speedup vs baseline: 1.1325x; 1.1325x over previous
//
#include <hip/hip_runtime.h>
#include <hip/hip_bf16.h>

#define BDIM 512

typedef __attribute__((ext_vector_type(8))) _Float16 f16x8;
typedef __attribute__((ext_vector_type(4))) _Float16 f16x4;
typedef __attribute__((ext_vector_type(4))) float f32x4;

// RoPE cos/sin table: tab[t*32+u] = (cos(t*invf_u), sin(t*invf_u)), t in [0,256), u in [0,32).
__global__ void rope_tab_kernel(float2* __restrict__ tab) {
    int idx = blockIdx.x * 256 + threadIdx.x;      // 8192 entries
    int t = idx >> 5, u = idx & 31;
    float inv = __expf((float)u * -0.28782313662425572f);  // 10000^(-u/32)
    float sn, cs;
    sincosf((float)t * inv, &sn, &cs);
    tab[idx] = make_float2(cs, sn);
}

// Local windowed attention with RoPE. b=32, n=4096, d=64, WINDOW=128, 1 backward window.
// One block per (batch, window): Q[128x64] x K/V[256x64]. 512 threads = 8 waves.
// QK^T swapped: D = mfma(K,Q) -> each lane holds P[i=c][j] -> softmax via shfl(16,32),
// P feeds PV straight from registers (A operand); V read with the SAME j-slot
// permutation (dot products are invariant under a shared k-relabeling).
// R2 structure (stage K AND V up front, one sync, no long-lived reg payload — R3's
// reg-held V caused scratch spills: WRITE_SIZE 33->74MB) + RoPE table + tile skips.
template<bool USE_TAB>
__global__ __launch_bounds__(512, 4)
void la_kernel(const float* __restrict__ qg, const float* __restrict__ kg,
               const float* __restrict__ vg, float* __restrict__ outg,
               const float2* __restrict__ tab)
{
    __shared__ _Float16 Ks[256][72];   // stride 144B -> 2-way bank alias (free)
    __shared__ _Float16 Vt[64][268];   // stride 536B; 8B-aligned rows for b64

    const int ww = blockIdx.x, bb = blockIdx.y;
    const int tid = threadIdx.x;
    const size_t qbase = ((size_t)bb * 4096 + (size_t)ww * 128) * 64;
    const float NEG = -3.0e38f;
    const float NLT32 = -0.28782313662425572f;
    const int srow0 = ww * 128 - 128;              // first K/V source row (may be <0)

    const int wv = tid >> 6, lane = tid & 63, g = lane >> 4, c = lane & 15;
    const int qrow = wv * 16 + c;

    // ---- per-lane Q load + RoPE (t = 128 + qrow) ----
    f16x8 qa0, qa1;
    {
        const float* p = qg + qbase + (size_t)qrow * 64 + 8 * g;
        float4 a0 = *(const float4*)p;
        float4 a1 = *(const float4*)(p + 4);
        float4 b0 = *(const float4*)(p + 32);
        float4 b1 = *(const float4*)(p + 36);
        float ra[8] = {a0.x,a0.y,a0.z,a0.w,a1.x,a1.y,a1.z,a1.w};
        float rb[8] = {b0.x,b0.y,b0.z,b0.w,b1.x,b1.y,b1.z,b1.w};
        float tq = (float)(128 + qrow);
        #pragma unroll
        for (int u = 0; u < 8; ++u) {
            float sn, cs;
            if (USE_TAB) {
                float2 t2 = tab[(128 + qrow) * 32 + 8 * g + u];
                cs = t2.x; sn = t2.y;
            } else {
                float invf = __expf((float)(8 * g + u) * NLT32);
                __sincosf(tq * invf, &sn, &cs);
            }
            float a = ra[u] * 0.125f, b = rb[u] * 0.125f;
            qa0[u] = (_Float16)(a * cs - b * sn);
            qa1[u] = (_Float16)(b * cs + a * sn);
        }
    }

    // ---- K staging with RoPE (t = j), b64 LDS writes ----
    #pragma unroll
    for (int it = 0; it < 4; ++it) {
        int task = tid + it * 512;                 // 2048 tasks
        int j = task >> 3, cb = (task & 7) << 2;
        float4 x1 = {0.f,0.f,0.f,0.f}, x2 = {0.f,0.f,0.f,0.f};
        int src = srow0 + j;
        if (src >= 0) {
            const float* p = kg + ((size_t)bb * 4096 + src) * 64 + cb;
            x1 = *(const float4*)p;
            x2 = *(const float4*)(p + 32);
        }
        const float* x1p = &x1.x;
        const float* x2p = &x2.x;
        f16x4 lo, hi;
        #pragma unroll
        for (int u = 0; u < 4; ++u) {
            float sn, cs;
            if (USE_TAB) {
                float2 t2 = tab[j * 32 + cb + u];
                cs = t2.x; sn = t2.y;
            } else {
                float invf = __expf((float)(cb + u) * NLT32);
                __sincosf((float)j * invf, &sn, &cs);
            }
            lo[u] = (_Float16)(x1p[u] * cs - x2p[u] * sn);
            hi[u] = (_Float16)(x2p[u] * cs + x1p[u] * sn);
        }
        *(f16x4*)&Ks[j][cb]      = lo;
        *(f16x4*)&Ks[j][cb + 32] = hi;
    }

    // ---- V staging: row-major float4 loads, transposed 4x4 f16 blocks, b64 writes ----
    #pragma unroll
    for (int tt = 0; tt < 2; ++tt) {
        int task = tid + tt * 512;
        int eq = task & 15, jq = task >> 4;        // jq in [0,64): 4-row group
        float4 x[4];
        #pragma unroll
        for (int u = 0; u < 4; ++u) {
            int src = srow0 + 4 * jq + u;
            float4 z = {0.f, 0.f, 0.f, 0.f};
            x[u] = (src >= 0)
                ? *(const float4*)(vg + ((size_t)bb * 4096 + src) * 64 + 4 * eq) : z;
        }
        #pragma unroll
        for (int w = 0; w < 4; ++w) {
            const float* xp = (const float*)&x[0];
            f16x4 o;
            o[0] = (_Float16)((const float*)&x[0])[w];
            o[1] = (_Float16)((const float*)&x[1])[w];
            o[2] = (_Float16)((const float*)&x[2])[w];
            o[3] = (_Float16)((const float*)&x[3])[w];
            (void)xp;
            *(f16x4*)&Vt[4 * eq + w][4 * jq] = o;
        }
    }

    __syncthreads();

    // ---- QK^T (swapped): acc[jt] holds D[j = 16jt+4g+r][i = c] ----
    f32x4 acc[16];
    #pragma unroll
    for (int jt = 0; jt < 16; ++jt) acc[jt] = (f32x4){0.f,0.f,0.f,0.f};

    #pragma unroll
    for (int jt = 0; jt < 16; ++jt) {
        if (jt <= wv + 8) {                        // wave-uniform: rest fully masked
            f16x8 kb0 = *(const f16x8*)&Ks[jt * 16 + c][8 * g];
            f16x8 kb1 = *(const f16x8*)&Ks[jt * 16 + c][32 + 8 * g];
            acc[jt] = __builtin_amdgcn_mfma_f32_16x16x32_f16(kb0, qa0, acc[jt], 0, 0, 0);
            acc[jt] = __builtin_amdgcn_mfma_f32_16x16x32_f16(kb1, qa1, acc[jt], 0, 0, 0);
        }
    }

    // ---- mask + softmax over j for row i = qrow ----
    const bool w0 = (ww == 0);
    #pragma unroll
    for (int jt = 0; jt < 16; ++jt) {
        #pragma unroll
        for (int r = 0; r < 4; ++r) {
            int j = jt * 16 + 4 * g + r;
            if ((j > qrow + 128) || (w0 && j < 128)) acc[jt][r] = NEG;
        }
    }

    float m = NEG;
    #pragma unroll
    for (int jt = 0; jt < 16; ++jt)
        #pragma unroll
        for (int r = 0; r < 4; ++r) m = fmaxf(m, acc[jt][r]);
    m = fmaxf(m, __shfl_xor(m, 16));
    m = fmaxf(m, __shfl_xor(m, 32));

    float s = 0.f;
    #pragma unroll
    for (int jt = 0; jt < 16; ++jt) {
        #pragma unroll
        for (int r = 0; r < 4; ++r) {
            float p = __expf(acc[jt][r] - m);      // masked -> underflows to 0
            acc[jt][r] = p;
            s += p;
        }
    }
    s += __shfl_xor(s, 16);
    s += __shfl_xor(s, 32);
    float rcp = 1.0f / s;

    // P -> f16 A-fragments
    f16x8 pa[8];
    #pragma unroll
    for (int s8 = 0; s8 < 8; ++s8)
        #pragma unroll
        for (int r = 0; r < 4; ++r) {
            pa[s8][r]     = (_Float16)(acc[2 * s8][r] * rcp);
            pa[s8][r + 4] = (_Float16)(acc[2 * s8 + 1][r] * rcp);
        }

    // ---- PV: A = P (regs), B = V with the SAME j-slot permutation ----
    f32x4 accO[4];
    #pragma unroll
    for (int nt = 0; nt < 4; ++nt) accO[nt] = (f32x4){0.f,0.f,0.f,0.f};

    #pragma unroll
    for (int s8 = 0; s8 < 8; ++s8) {
        if (32 * s8 <= 16 * wv + 143) {            // wave-uniform: rest have P == 0
            #pragma unroll
            for (int nt = 0; nt < 4; ++nt) {
                f16x4 vb0 = *(const f16x4*)&Vt[nt * 16 + c][s8 * 32 + 4 * g];
                f16x4 vb1 = *(const f16x4*)&Vt[nt * 16 + c][s8 * 32 + 16 + 4 * g];
                f16x8 vb;
                #pragma unroll
                for (int u = 0; u < 4; ++u) { vb[u] = vb0[u]; vb[u + 4] = vb1[u]; }
                accO[nt] = __builtin_amdgcn_mfma_f32_16x16x32_f16(pa[s8], vb, accO[nt], 0, 0, 0);
            }
        }
    }

    // ---- store: i = wv*16 + 4g + r, e = nt*16 + c ----
    float* op = outg + qbase + (size_t)(wv * 16) * 64;
    #pragma unroll
    for (int nt = 0; nt < 4; ++nt)
        #pragma unroll
        for (int r = 0; r < 4; ++r)
            op[(size_t)(4 * g + r) * 64 + nt * 16 + c] = accO[nt][r];
}

extern "C" void kernel_launch(void* const* d_in, const int* in_sizes, int n_in,
                              void* d_out, int out_size, void* d_ws, size_t ws_size,
                              hipStream_t stream) {
    (void)in_sizes; (void)n_in; (void)out_size;
    const float* q = (const float*)d_in[0];
    const float* k = (const float*)d_in[1];
    const float* v = (const float*)d_in[2];
    float* out = (float*)d_out;
    dim3 grid(32, 32);  // x = window, y = batch

    if (ws_size >= 8192 * sizeof(float2)) {
        float2* tab = (float2*)d_ws;
        rope_tab_kernel<<<32, 256, 0, stream>>>(tab);
        la_kernel<true><<<grid, BDIM, 0, stream>>>(q, k, v, out, tab);
    } else {
        la_kernel<false><<<grid, BDIM, 0, stream>>>(q, k, v, out, nullptr);
    }
}